// Round 7
// baseline (66.796 us; speedup 1.0000x reference)
//
#include <hip/hip_runtime.h>
#include <math.h>

#define B_    2
#define C_    512
#define H_    64
#define W_    32
#define S_    2048
#define QKC_  576
#define INNER_ 512
#define NH_   8
#define HD_   64
#define TWO_PI_ 6.283185307179586f

typedef __attribute__((ext_vector_type(8))) short bfrag;
typedef __attribute__((ext_vector_type(4))) float ffrag;
typedef __attribute__((ext_vector_type(16))) float f16v;

typedef __attribute__((address_space(1))) const unsigned int as1_u32;
typedef __attribute__((address_space(3))) unsigned int as3_u32;

__device__ __forceinline__ ushort f2bf(float f) {
    unsigned u = __builtin_bit_cast(unsigned, f);
    unsigned r = (u + 0x7FFFu + ((u >> 16) & 1u)) >> 16;
    return (ushort)r;
}

__device__ __forceinline__ f16v zero16() {
    f16v z;
    #pragma unroll
    for (int i = 0; i < 16; i++) z[i] = 0.f;
    return z;
}

#define GLD(gp_, lp_) __builtin_amdgcn_global_load_lds((as1_u32*)(gp_), (as3_u32*)(lp_), 16, 0, 0)
#define EXPA(dst_, x_) asm("v_exp_f32 %0, %1" : "=v"(dst_) : "v"(x_))
#define SC_LOG2E 0.18033688011f   /* 0.125 * log2(e) */

// ---------------- X[:,0:512] = transpose(hidden); X[:,512:576] = embeddings ----------------
__global__ void k_trans_emb(const float* __restrict__ hid, ushort* __restrict__ X) {
    __shared__ float t[32][33];
    int b  = blockIdx.z;
    int s0 = blockIdx.x * 32, c0 = blockIdx.y * 32;
    int tx = threadIdx.x, ty = threadIdx.y;
    if (c0 < 512) {
        t[ty][tx] = hid[((size_t)b * C_ + (c0 + ty)) * S_ + s0 + tx];
        __syncthreads();
        X[((size_t)(b * S_ + s0 + ty)) * QKC_ + c0 + tx] = f2bf(t[tx][ty]);
    } else {
        int c = c0 - 512 + tx;
        int s = s0 + ty;
        int h = s >> 5, w = s & 31;
        float val;
        if (c < 32) {
            int f = c >> 1;
            int n = h * 16 + f;
            float lx = (n == 0) ? -2.0f : log2f((float)n);
            float arg = lx * (float)(f + 1);
            val = (c & 1) ? sinf(arg) : cosf(arg);
        } else {
            int tt = (c - 32) >> 1;
            float theta = ((float)tt + 0.5f) * (float)(w * 16 + tt) * (TWO_PI_ / 512.0f);
            val = (c & 1) ? sinf(theta) : cosf(theta);
        }
        X[(size_t)(b * S_ + s) * QKC_ + c0 + tx] = f2bf(val);
    }
}

// ---------------- all 4 weight transposes in one launch ----------------
__global__ void k_wtrans_all(const float* __restrict__ Wq, const float* __restrict__ Wk,
                             const float* __restrict__ Wv, const float* __restrict__ Wo,
                             ushort* __restrict__ Wqt, ushort* __restrict__ Wkt,
                             ushort* __restrict__ Wvt, ushort* __restrict__ Wot) {
    __shared__ float t[32][33];
    int z = blockIdx.z;
    const float* W; ushort* Wt; int K;
    if (z == 0)      { W = Wq; Wt = Wqt; K = QKC_; }
    else if (z == 1) { W = Wk; Wt = Wkt; K = QKC_; }
    else if (z == 2) { W = Wv; Wt = Wvt; K = C_; }
    else             { W = Wo; Wt = Wot; K = INNER_; }
    int k0 = blockIdx.x * 32, n0 = blockIdx.y * 32;
    if (k0 >= K) return;
    int tx = threadIdx.x, ty = threadIdx.y;
    t[ty][tx] = W[(size_t)(k0 + ty) * 512 + n0 + tx];
    __syncthreads();
    Wt[(size_t)(n0 + ty) * K + k0 + tx] = f2bf(t[tx][ty]);
}

// ---------------- fused QKV GEMM: Q row-major; K,V written in MFMA-packed layouts ----------
// Kpk[pair16][kvb64][sl8][kv32][8d]   (sl = d>>3)    4 MB
// Vpk[pair16][kvb64][sl4][d64][8kv]   (sl = (kv&31)>>3) 4 MB
#define GSTAGE(buf_, k0_) {                                                   \
    _Pragma("unroll")                                                         \
    for (int i_ = 0; i_ < 6; i_++)                                            \
        GLD(gp[i_] + (k0_), tl + (buf_) * 12288 + lo[i_]); }

__global__ __launch_bounds__(256, 3) void k_qkv(const ushort* __restrict__ X,
                                                const ushort* __restrict__ Wqt,
                                                const ushort* __restrict__ Wkt,
                                                const ushort* __restrict__ Wvt,
                                                ushort* __restrict__ Qb,
                                                ushort* __restrict__ Kpk,
                                                ushort* __restrict__ Vpk) {
    __shared__ ushort __attribute__((aligned(16))) tl[2 * 12288];   // 48 KB

    int tid = threadIdx.x;
    int l = tid & 63, wv = tid >> 6;
    int wr = wv >> 1, wc = wv & 1;
    int bid = blockIdx.x;
    int lgc = (bid & 7) * 96 + (bid >> 3);
    int bx = lgc % 24, by = lgc / 24;
    int n0 = bx * 64, m0 = by * 128;
    int sel = n0 >> 9, n0l = n0 & 511;
    const ushort* Bt = (sel == 0) ? Wqt : (sel == 1) ? Wkt : Wvt;
    const int K = (sel < 2) ? QKC_ : C_;
    const int nst = K >> 6;
    int l15 = l & 15, lg = l >> 4;
    int swz = l15 & 7;

    const ushort* gp[6];
    unsigned lo[6];
    {
        int rsub = l >> 3;
        int clog = (l & 7) ^ rsub;
        #pragma unroll
        for (int i = 0; i < 6; i++) {
            int c = wv * 6 + i;
            lo[i] = c * 512;
            if (c < 16) gp[i] = X  + (size_t)(m0  + c * 8        + rsub) * QKC_ + clog * 8;
            else        gp[i] = Bt + (size_t)(n0l + (c - 16) * 8 + rsub) * K    + clog * 8;
        }
    }

    ffrag acc[4][2];
    #pragma unroll
    for (int i = 0; i < 4; i++)
        #pragma unroll
        for (int j = 0; j < 2; j++) acc[i][j] = (ffrag){0.f, 0.f, 0.f, 0.f};

    GSTAGE(0, 0);
    int cur = 0;
    for (int kt = 0; kt < nst; kt++) {
        __syncthreads();
        if (kt + 1 < nst) GSTAGE(cur ^ 1, (kt + 1) * 64);
        const ushort* As = tl + cur * 12288;
        const ushort* Bs = As + 8192;
        #pragma unroll
        for (int ks = 0; ks < 2; ks++) {
            int cl = ks * 4 + lg;
            int ch = (cl ^ swz) * 8;
            bfrag af[4], bf[2];
            #pragma unroll
            for (int mi = 0; mi < 4; mi++)
                af[mi] = *(const bfrag*)(As + (wr * 64 + mi * 16 + l15) * 64 + ch);
            #pragma unroll
            for (int nj = 0; nj < 2; nj++)
                bf[nj] = *(const bfrag*)(Bs + (wc * 32 + nj * 16 + l15) * 64 + ch);
            #pragma unroll
            for (int mi = 0; mi < 4; mi++)
                #pragma unroll
                for (int nj = 0; nj < 2; nj++)
                    acc[mi][nj] = __builtin_amdgcn_mfma_f32_16x16x32_bf16(af[mi], bf[nj], acc[mi][nj], 0, 0, 0);
        }
        cur ^= 1;
    }

    if (sel == 0) {
        // Q: row-major bf16
        #pragma unroll
        for (int mi = 0; mi < 4; mi++)
            #pragma unroll
            for (int nj = 0; nj < 2; nj++)
                #pragma unroll
                for (int r = 0; r < 4; r++) {
                    int row = m0 + wr * 64 + mi * 16 + lg * 4 + r;
                    int col = n0l + wc * 32 + nj * 16 + l15;
                    Qb[(size_t)row * INNER_ + col] = f2bf(acc[mi][nj][r]);
                }
    } else {
        // LDS transpose: Ct[n64][m128]
        ushort (*Ct)[136] = (ushort(*)[136])tl;
        __syncthreads();
        #pragma unroll
        for (int mi = 0; mi < 4; mi++)
            #pragma unroll
            for (int nj = 0; nj < 2; nj++)
                #pragma unroll
                for (int r = 0; r < 4; r++)
                    Ct[wc * 32 + nj * 16 + l15][wr * 64 + mi * 16 + lg * 4 + r] = f2bf(acc[mi][nj][r]);
        __syncthreads();
        int pair = (m0 >> 11) * 8 + (n0l >> 6);
        int kvb0 = (m0 & 2047) >> 5;
        if (sel == 1) {
            // K packed: chunk = (sl, kv): 8 consecutive d at fixed kv
            #pragma unroll
            for (int p = 0; p < 4; p++) {
                int cid = tid + p * 256;
                int sl = cid >> 7, kv = cid & 127;
                bfrag tmp;
                #pragma unroll
                for (int j = 0; j < 8; j++) tmp[j] = (short)Ct[sl * 8 + j][kv];
                ushort* dst = Kpk + ((size_t)((pair * 64 + kvb0 + (kv >> 5)) * 8 + sl)) * 256 + (kv & 31) * 8;
                *(uint4*)dst = __builtin_bit_cast(uint4, tmp);
            }
        } else {
            // V packed: chunk = (d, mc): 8 consecutive kv at fixed d (contiguous in Ct row)
            #pragma unroll
            for (int p = 0; p < 4; p++) {
                int cid = tid + p * 256;
                int d = cid >> 4, mc = cid & 15;
                uint4 v = *(uint4*)&Ct[d][mc * 8];
                ushort* dst = Vpk + ((size_t)((pair * 64 + kvb0 + (mc >> 2)) * 4 + (mc & 3))) * 512 + d * 8;
                *(uint4*)dst = v;
            }
        }
    }
}

// ---------------- output GEMM + bias + transpose + residual (unchanged) ----------------
__global__ __launch_bounds__(256, 2) void k_og(const ushort* __restrict__ Ob,
                                               const ushort* __restrict__ Wot,
                                               const float* __restrict__ bias,
                                               const float* __restrict__ hid,
                                               float* __restrict__ out) {
    __shared__ ushort __attribute__((aligned(16))) tl[2 * 12288];

    int tid = threadIdx.x;
    int l = tid & 63, wv = tid >> 6;
    int wr = wv >> 1, wc = wv & 1;
    int bid = blockIdx.x;
    int lgc = (bid & 7) * 32 + (bid >> 3);
    int bx = lgc & 7, by = lgc >> 3;
    int n0 = bx * 64, m0 = by * 128;
    int l15 = l & 15, lg = l >> 4;
    int swz = l15 & 7;

    const ushort* gp[6];
    unsigned lo[6];
    {
        int rsub = l >> 3;
        int clog = (l & 7) ^ rsub;
        #pragma unroll
        for (int i = 0; i < 6; i++) {
            int c = wv * 6 + i;
            lo[i] = c * 512;
            if (c < 16) gp[i] = Ob  + (size_t)(m0 + c * 8        + rsub) * INNER_ + clog * 8;
            else        gp[i] = Wot + (size_t)(n0 + (c - 16) * 8 + rsub) * INNER_ + clog * 8;
        }
    }

    ffrag acc[4][2];
    #pragma unroll
    for (int i = 0; i < 4; i++)
        #pragma unroll
        for (int j = 0; j < 2; j++) acc[i][j] = (ffrag){0.f, 0.f, 0.f, 0.f};

    GSTAGE(0, 0);
    int cur = 0;
    for (int kt = 0; kt < 8; kt++) {
        __syncthreads();
        if (kt < 7) GSTAGE(cur ^ 1, (kt + 1) * 64);
        const ushort* As = tl + cur * 12288;
        const ushort* Bs = As + 8192;
        #pragma unroll
        for (int ks = 0; ks < 2; ks++) {
            int cl = ks * 4 + lg;
            int ch = (cl ^ swz) * 8;
            bfrag af[4], bf[2];
            #pragma unroll
            for (int mi = 0; mi < 4; mi++)
                af[mi] = *(const bfrag*)(As + (wr * 64 + mi * 16 + l15) * 64 + ch);
            #pragma unroll
            for (int nj = 0; nj < 2; nj++)
                bf[nj] = *(const bfrag*)(Bs + (wc * 32 + nj * 16 + l15) * 64 + ch);
            #pragma unroll
            for (int mi = 0; mi < 4; mi++)
                #pragma unroll
                for (int nj = 0; nj < 2; nj++)
                    acc[mi][nj] = __builtin_amdgcn_mfma_f32_16x16x32_bf16(af[mi], bf[nj], acc[mi][nj], 0, 0, 0);
        }
        cur ^= 1;
    }

    float (*Cf)[129] = (float(*)[129])tl;
    float bv[2];
    #pragma unroll
    for (int nj = 0; nj < 2; nj++) bv[nj] = bias[n0 + wc * 32 + nj * 16 + l15];
    __syncthreads();
    #pragma unroll
    for (int mi = 0; mi < 4; mi++)
        #pragma unroll
        for (int nj = 0; nj < 2; nj++)
            #pragma unroll
            for (int r = 0; r < 4; r++)
                Cf[wc * 32 + nj * 16 + l15][wr * 64 + mi * 16 + lg * 4 + r] = acc[mi][nj][r] + bv[nj];
    __syncthreads();
    int b = m0 >> 11, s0m = m0 & 2047;
    #pragma unroll
    for (int p = 0; p < 8; p++) {
        int f = p * 256 + tid;
        int c = f >> 5, sq = (f & 31) * 4;
        size_t o = (((size_t)(b * 512 + n0 + c)) << 11) + s0m + sq;
        float4 hv = *(const float4*)(hid + o);
        float4 cv = *(float4*)&Cf[c][sq];
        cv.x += hv.x; cv.y += hv.y; cv.z += hv.z; cv.w += hv.w;
        *(float4*)(out + o) = cv;
    }
}

// ---------------- flash attention: 8 waves = 2 q-groups x 4 KV-splits ----------------
// grid 512 (XCD-swizzled: 64 blocks per pair, pair-major per XCD). KVBLK=32/iter, 16 iters.
// K/V staged from packed layouts via linear global_load_lds; conflict-free ds_read_b128.
#define CVTPK(dst, a, b) asm("v_cvt_pk_bf16_f32 %0, %1, %2" : "=v"(dst) : "v"(a), "v"(b))
#define SWAP32(a, b)     asm("v_permlane32_swap_b32 %0, %1" : "+v"(a), "+v"(b))

#define ASTAGE(buf_, kt_) {                                                   \
    const ushort* g_ = (qg ? vpb : kpb) + (size_t)(kt_) * 2048 + l * 8;       \
    ushort* lp_ = ktv + spb + (buf_) * 4096 + (qg ? 2048 : 0);                \
    _Pragma("unroll")                                                         \
    for (int i_ = 0; i_ < 4; i_++)                                            \
        GLD(g_ + i_ * 512, lp_ + i_ * 512); }

__global__ __launch_bounds__(512, 4) void k_attn(const ushort* __restrict__ Qf,
                                                 const ushort* __restrict__ Kpk,
                                                 const ushort* __restrict__ Vpk,
                                                 ushort* __restrict__ Ob) {
    __shared__ __attribute__((aligned(16))) char smem[69632];
    ushort* ktv = (ushort*)smem;            // loop: [sp4][buf2][K 2048 | V 2048] elems (64 KB)
    float*  cmb = (float*)smem;             // epilogue: [8][64][33] f32 (67.6 KB)
    float*  mlsh = (float*)(smem + 67584);  // [8][{m,l}][32]

    const int id = blockIdx.x;              // 512 blocks
    const int lgc = (id & 7) * 64 + (id >> 3);
    const int qb = lgc & 31, pair = lgc >> 5;
    const int hd = pair & 7, b = pair >> 3;

    const int tid = threadIdx.x;
    const int l = tid & 63, wv = tid >> 6;
    const int qg = wv >> 2, sp = wv & 3;
    const int l31 = l & 31, hi = l >> 5;
    const int hoff = hd * HD_;
    const int brow = b * S_ + qb * 64;

    // Q fragments (B-operand: lane = q col, elems d = ks*16 + hi*8 ..)
    bfrag qf[4];
    {
        const ushort* qp = Qf + (size_t)(brow + qg * 32 + l31) * INNER_ + hoff + hi * 8;
        #pragma unroll
        for (int ks = 0; ks < 4; ks++) qf[ks] = *(const bfrag*)(qp + ks * 16);
    }

    const ushort* kpb = Kpk + ((size_t)pair * 64 + sp * 16) * 2048;
    const ushort* vpb = Vpk + ((size_t)pair * 64 + sp * 16) * 2048;
    const int spb  = sp * 8192;              // LDS elem base for this split
    const int koff = l31 * 8 + hi * 256;     // K read: + ks*512
    const int voff = l31 * 8 + hi * 512;     // V read: + s*1024 (+256 for acc1)

    ASTAGE(0, 0);

    float m_run = -INFINITY, l_run = 0.f;
    f16v acc0 = zero16(), acc1 = zero16();
    int buf = 0;

    for (int kt = 0; kt < 16; kt++) {
        __syncthreads();                     // tile(buf) landed; prev reads of buf^1 done
        if (kt < 15) ASTAGE(buf ^ 1, kt + 1);

        const ushort* Kt = ktv + spb + buf * 4096;
        const ushort* Vt = Kt + 2048;

        // ---- S = K Q^T: lane q = l31, kv rows (j&3)+8*(j>>2)+4*hi of this 32-tile ----
        f16v sf0 = zero16();
        #pragma unroll
        for (int ks = 0; ks < 4; ks++) {
            bfrag kfr = *(const bfrag*)(Kt + ks * 512 + koff);
            sf0 = __builtin_amdgcn_mfma_f32_32x32x16_bf16(kfr, qf[ks], sf0, 0, 0, 0);
        }

        // ---- online softmax (tree reductions) ----
        float t8[8];
        #pragma unroll
        for (int j = 0; j < 8; j++) t8[j] = fmaxf(sf0[j], sf0[j + 8]);
        float t4a = fmaxf(t8[0], t8[4]), t4b = fmaxf(t8[1], t8[5]);
        float t4c = fmaxf(t8[2], t8[6]), t4d = fmaxf(t8[3], t8[7]);
        float tm = fmaxf(fmaxf(t4a, t4b), fmaxf(t4c, t4d));
        tm = fmaxf(tm, __shfl_xor(tm, 32));
        if (!__all(tm <= m_run + 64.0f)) {   // defer-max: 8 nats in raw units
            float mn = fmaxf(m_run, tm);
            float corr; EXPA(corr, (m_run - mn) * SC_LOG2E);
            l_run *= corr;
            #pragma unroll
            for (int j = 0; j < 16; j++) { acc0[j] *= corr; acc1[j] *= corr; }
            m_run = mn;
        }
        float nm = -m_run * SC_LOG2E;
        #pragma unroll
        for (int j = 0; j < 16; j++) { float p; EXPA(p, fmaf(sf0[j], SC_LOG2E, nm)); sf0[j] = p; }
        float s8[8];
        #pragma unroll
        for (int j = 0; j < 8; j++) s8[j] = sf0[j] + sf0[j + 8];
        float ls = ((s8[0] + s8[4]) + (s8[1] + s8[5])) + ((s8[2] + s8[6]) + (s8[3] + s8[7]));
        ls += __shfl_xor(ls, 32);
        l_run += ls;

        // ---- O^T += V^T P : A = V^T (reg-packed LDS), B = P (in-register) ----
        #pragma unroll
        for (int s = 0; s < 2; s++) {
            unsigned A0, B0, A1, B1;
            CVTPK(A0, sf0[s * 8 + 0], sf0[s * 8 + 1]); CVTPK(B0, sf0[s * 8 + 4], sf0[s * 8 + 5]);
            SWAP32(A0, B0);
            CVTPK(A1, sf0[s * 8 + 2], sf0[s * 8 + 3]); CVTPK(B1, sf0[s * 8 + 6], sf0[s * 8 + 7]);
            SWAP32(A1, B1);
            uint4 u; u.x = A0; u.y = A1; u.z = B0; u.w = B1;
            bfrag pa = __builtin_bit_cast(bfrag, u);
            bfrag v0 = *(const bfrag*)(Vt + s * 1024 + voff);
            bfrag v1 = *(const bfrag*)(Vt + s * 1024 + voff + 256);
            acc0 = __builtin_amdgcn_mfma_f32_32x32x16_bf16(v0, pa, acc0, 0, 0, 0);
            acc1 = __builtin_amdgcn_mfma_f32_32x32x16_bf16(v1, pa, acc1, 0, 0, 0);
        }

        buf ^= 1;
    }

    // ---- 4-way combine across KV-splits, per q-group ----
    if (hi == 0) {
        mlsh[(qg * 4 + sp) * 64 + l31]      = m_run;
        mlsh[(qg * 4 + sp) * 64 + 32 + l31] = l_run;
    }
    __syncthreads();                         // all tile reads done; cmb may overwrite ktv
    {
        float* creg = cmb + (qg * 4 + sp) * 2112;
        #pragma unroll
        for (int j = 0; j < 16; j++) {
            int d0 = (j & 3) + 8 * (j >> 2) + 4 * hi;
            creg[d0 * 33 + l31]        = acc0[j];
            creg[(d0 + 32) * 33 + l31] = acc1[j];
        }
    }
    __syncthreads();
    {
        int qgE = tid >> 8;
        int t2 = tid & 255;
        int qq = t2 >> 3, cc = t2 & 7;
        float mh[4], lh[4], cs[4];
        float mg = -INFINITY;
        #pragma unroll
        for (int h = 0; h < 4; h++) {
            mh[h] = mlsh[(qgE * 4 + h) * 64 + qq];
            lh[h] = mlsh[(qgE * 4 + h) * 64 + 32 + qq];
            mg = fmaxf(mg, mh[h]);
        }
        float tot = 0.f;
        #pragma unroll
        for (int h = 0; h < 4; h++) { EXPA(cs[h], (mh[h] - mg) * SC_LOG2E); tot += cs[h] * lh[h]; }
        float inv = 1.0f / tot;
        bfrag ov;
        #pragma unroll
        for (int j = 0; j < 8; j++) {
            int d = cc * 8 + j;
            float s = 0.f;
            #pragma unroll
            for (int h = 0; h < 4; h++) s += cs[h] * cmb[(qgE * 4 + h) * 2112 + d * 33 + qq];
            ov[j] = (short)f2bf(s * inv);
        }
        *(uint4*)(Ob + (size_t)(brow + qgE * 32 + qq) * INNER_ + hoff + cc * 8) = __builtin_bit_cast(uint4, ov);
    }
}

extern "C" void kernel_launch(void* const* d_in, const int* in_sizes, int n_in,
                              void* d_out, int out_size, void* d_ws, size_t ws_size,
                              hipStream_t stream) {
    const float* hid  = (const float*)d_in[0];
    const float* Wq   = (const float*)d_in[1];
    const float* Wk   = (const float*)d_in[2];
    const float* Wv   = (const float*)d_in[3];
    const float* Wout = (const float*)d_in[4];
    const float* bout = (const float*)d_in[5];
    float* out = (float*)d_out;

    const int M = B_ * S_;   // 4096
    char* w = (char*)d_ws;
    ushort* X    = (ushort*)w;                    w += (size_t)M * QKC_ * 2;
    ushort* Qb   = (ushort*)w;                    w += (size_t)M * INNER_ * 2;
    ushort* Kpk  = (ushort*)w;                    w += (size_t)M * INNER_ * 2;   // packed
    ushort* Vpk  = (ushort*)w;                    w += (size_t)M * INNER_ * 2;   // packed
    ushort* Ob   = (ushort*)w;                    w += (size_t)M * INNER_ * 2;
    ushort* Wqt  = (ushort*)w;                    w += (size_t)INNER_ * QKC_ * 2;
    ushort* Wkt  = (ushort*)w;                    w += (size_t)INNER_ * QKC_ * 2;
    ushort* Wvt  = (ushort*)w;                    w += (size_t)INNER_ * C_ * 2;
    ushort* Wot  = (ushort*)w;                    w += (size_t)C_ * INNER_ * 2;

    k_wtrans_all<<<dim3(18, 16, 4), dim3(32, 32), 0, stream>>>(Wq, Wk, Wv, Wout,
                                                               Wqt, Wkt, Wvt, Wot);
    k_trans_emb<<<dim3(S_ / 32, 18, B_), dim3(32, 32), 0, stream>>>(hid, X);

    k_qkv<<<dim3(768), 256, 0, stream>>>(X, Wqt, Wkt, Wvt, Qb, Kpk, Vpk);

    k_attn<<<dim3(512), 512, 0, stream>>>(Qb, Kpk, Vpk, Ob);

    k_og<<<dim3(256), 256, 0, stream>>>(Ob, Wot, bout, hid, out);
}